// Round 4
// baseline (120.564 us; speedup 1.0000x reference)
//
#include <hip/hip_runtime.h>
#include <cstdint>
#include <cstddef>

typedef __attribute__((ext_vector_type(4))) float f32x4;
typedef __bf16 bf16x8 __attribute__((ext_vector_type(8)));
typedef __attribute__((ext_vector_type(4))) unsigned int u32x4;
typedef __attribute__((ext_vector_type(2))) unsigned int u32x2;

#define DEVI __device__ __forceinline__

static constexpr int NB = 4;      // batches
static constexpr int NPTS = 8192; // N query points
static constexpr int SPTS = 2048; // S source points
static constexpr int DF = 256;    // feature dim of points1/points2
static constexpr int CIN = 512;   // concat width = 2*DF = K of GEMM1
static constexpr int MTOT = NB * NPTS; // 32768 rows

DEVI unsigned short f2b(float f) {
  union { float f; unsigned u; } v; v.f = f;
  unsigned r = v.u + 0x7FFFu + ((v.u >> 16) & 1u);
  return (unsigned short)(r >> 16);
}
DEVI float b2f(unsigned short h) {
  union { unsigned u; float f; } v; v.u = ((unsigned)h) << 16;
  return v.f;
}

typedef const __attribute__((address_space(1))) unsigned int* gas_t;
typedef __attribute__((address_space(3))) unsigned int* las_t;
DEVI void gload16(const void* g, void* l) {
  // async global->LDS, 16B per lane; LDS dest = uniform base + lane*16
  __builtin_amdgcn_global_load_lds((gas_t)g, (las_t)l, 16, 0, 0);
}

// ---------------- BN param folding: scale = g*rsqrt(v+eps); shift = (b-m)*scale + be
__global__ __launch_bounds__(512) void params_kernel(
    const float* __restrict__ b0, const float* __restrict__ g0, const float* __restrict__ be0,
    const float* __restrict__ m0, const float* __restrict__ v0,
    const float* __restrict__ b1, const float* __restrict__ g1, const float* __restrict__ be1,
    const float* __restrict__ m1, const float* __restrict__ v1,
    float* __restrict__ sc0, float* __restrict__ sh0,
    float* __restrict__ sc1, float* __restrict__ sh1) {
  int t = threadIdx.x;
  if (t < 512) {
    float s = g0[t] / sqrtf(v0[t] + 1e-3f);
    sc0[t] = s;
    sh0[t] = (b0[t] - m0[t]) * s + be0[t];
  }
  if (t < 256) {
    float s = g1[t] / sqrtf(v1[t] + 1e-3f);
    sc1[t] = s;
    sh1[t] = (b1[t] - m1[t]) * s + be1[t];
  }
}

// ---------------- tiled transpose + f32->bf16 cast.
__global__ __launch_bounds__(256) void transpose_cast_kernel(
    const float* __restrict__ in, unsigned short* __restrict__ out,
    int cols, int ldo, long ibs, long obs, int tilesPerRow) {
  __shared__ float tile[64][65];
  in += (size_t)blockIdx.y * ibs;
  out += (size_t)blockIdx.y * obs;
  const int tr = (blockIdx.x / tilesPerRow) * 64;
  const int tc = (blockIdx.x % tilesPerRow) * 64;
  const int lx = threadIdx.x & 63, ly = threadIdx.x >> 6;
#pragma unroll
  for (int i = ly; i < 64; i += 4)
    tile[i][lx] = in[(size_t)(tr + i) * cols + tc + lx];
  __syncthreads();
#pragma unroll
  for (int i = ly; i < 64; i += 4)
    out[(size_t)(tc + i) * ldo + tr + lx] = f2b(tile[lx][i]);
}

// ---------------- 3-NN, wave-parallel over S, branchless top-3.
__global__ __launch_bounds__(512) void knn_kernel(
    const float* __restrict__ xyz1, const float* __restrict__ xyz2,
    int* __restrict__ oidx, float* __restrict__ ow) {
  __shared__ f32x4 sp[SPTS];
  __shared__ float md[7][64][3];
  __shared__ int   mi[7][64][3];
  const int batch = blockIdx.x >> 7;           // 128 blocks per batch
  const int nbase = (blockIdx.x & 127) << 6;   // *64
  const float* xb = xyz2 + (size_t)batch * 3 * SPTS;
  for (int i = threadIdx.x; i < SPTS; i += 512) {
    float a = xb[i], b = xb[SPTS + i], c = xb[2 * SPTS + i];
    f32x4 v;
    v.x = a; v.y = b; v.z = c;
    v.w = __fadd_rn(__fadd_rn(__fmul_rn(a, a), __fmul_rn(b, b)), __fmul_rn(c, c));
    sp[i] = v;
  }
  __syncthreads();
  const int lane = threadIdx.x & 63, wave = threadIdx.x >> 6;
  const int n = nbase + lane;
  const float* q = xyz1 + (size_t)batch * 3 * NPTS;
  const float x = q[n], y = q[NPTS + n], z = q[2 * NPTS + n];
  const float qa = __fadd_rn(__fadd_rn(__fmul_rn(x, x), __fmul_rn(y, y)), __fmul_rn(z, z));
  float d0 = 3.4e38f, d1 = 3.4e38f, d2 = 3.4e38f;
  int i0 = 0, i1 = 0, i2 = 0;
  const int s0 = wave << 8;
#pragma unroll 8
  for (int s = s0; s < s0 + 256; ++s) {
    f32x4 v = sp[s];
    float dot = __builtin_fmaf(v.z, z, __builtin_fmaf(v.y, y, __fmul_rn(v.x, x)));
    float sq = __builtin_fmaf(-2.0f, dot, __fadd_rn(qa, v.w));
    const bool c0 = sq < d0, c1 = sq < d1, c2 = sq < d2;
    d2 = c1 ? d1 : (c2 ? sq : d2);
    i2 = c1 ? i1 : (c2 ? s : i2);
    d1 = c0 ? d0 : (c1 ? sq : d1);
    i1 = c0 ? i0 : (c1 ? s : i1);
    d0 = c0 ? sq : d0;
    i0 = c0 ? s : i0;
  }
  if (wave != 0) {
    md[wave - 1][lane][0] = d0; mi[wave - 1][lane][0] = i0;
    md[wave - 1][lane][1] = d1; mi[wave - 1][lane][1] = i1;
    md[wave - 1][lane][2] = d2; mi[wave - 1][lane][2] = i2;
  }
  __syncthreads();
  if (wave != 0) return;
#pragma unroll
  for (int w = 0; w < 7; ++w) {
#pragma unroll
    for (int j = 0; j < 3; ++j) {
      float sq = md[w][lane][j];
      int si = mi[w][lane][j];
      const bool c0 = sq < d0, c1 = sq < d1, c2 = sq < d2;
      d2 = c1 ? d1 : (c2 ? sq : d2);
      i2 = c1 ? i1 : (c2 ? si : i2);
      d1 = c0 ? d0 : (c1 ? sq : d1);
      i1 = c0 ? i0 : (c1 ? si : i1);
      d0 = c0 ? sq : d0;
      i0 = c0 ? si : i0;
    }
  }
  float w0 = 1.0f / fmaxf(d0, 1e-10f);
  float w1 = 1.0f / fmaxf(d1, 1e-10f);
  float w2 = 1.0f / fmaxf(d2, 1e-10f);
  float sum = __fadd_rn(__fadd_rn(w0, w1), w2);
  const int p = batch * NPTS + n;
  oidx[3 * p + 0] = i0; oidx[3 * p + 1] = i1; oidx[3 * p + 2] = i2;
  ow[3 * p + 0] = w0 / sum; ow[3 * p + 1] = w1 / sum; ow[3 * p + 2] = w2 / sum;
}

// ---------------- interpolation: one wave per point; gathers 3 contiguous bf16 rows.
__global__ __launch_bounds__(256) void interp_kernel(
    const unsigned short* __restrict__ p2t, const int* __restrict__ oidx,
    const float* __restrict__ ow, unsigned short* __restrict__ A) {
  const int lane = threadIdx.x & 63;
  const int p = blockIdx.x * 4 + (threadIdx.x >> 6);
  const int b = p >> 13;
  float a0 = 0.f, a1 = 0.f, a2 = 0.f, a3 = 0.f;
#pragma unroll
  for (int k = 0; k < 3; ++k) {
    const int id = oidx[3 * p + k];
    const float w = ow[3 * p + k];
    const unsigned short* row = p2t + ((size_t)b * SPTS + id) * DF + lane * 4;
    u32x2 v = *reinterpret_cast<const u32x2*>(row);
    a0 = __builtin_fmaf(w, b2f((unsigned short)(v.x & 0xffff)), a0);
    a1 = __builtin_fmaf(w, b2f((unsigned short)(v.x >> 16)), a1);
    a2 = __builtin_fmaf(w, b2f((unsigned short)(v.y & 0xffff)), a2);
    a3 = __builtin_fmaf(w, b2f((unsigned short)(v.y >> 16)), a3);
  }
  u32x2 o;
  o.x = (unsigned)f2b(a0) | ((unsigned)f2b(a1) << 16);
  o.y = (unsigned)f2b(a2) | ((unsigned)f2b(a3) << 16);
  *reinterpret_cast<u32x2*>(A + (size_t)p * CIN + DF + lane * 4) = o;
}

// ---------------- bf16 MFMA GEMM, counted-vmcnt pipeline (T3/T4).
// C[M,Nout] = A[M,512] * BT[Nout,512]^T. 128x128 tile, BK=64, 8 waves (4Mx2N),
// 16x16x32 MFMA. 3-deep LDS ring (96KB); global_load_lds w16 with pre-swizzled
// source + swizzled ds_read (both-sides rule #21). Per K-step: one raw
// s_barrier + s_waitcnt vmcnt(4) (per-wave: 4 gloads/tile -> tile t landed,
// tile t+1 in flight). stage(t+2) issued after the barrier: all tile-(t-1)
// reads precede barrier(t) precede the overwrite of slot (t-1)%3.
// EPI 0: H = bf16(relu(c*scale+shift)), row-major [M][512]
// EPI 1: out f32 [B][256][N]: out[(row>>13)*256+col][row&8191]
template <int EPI>
__global__ __launch_bounds__(512) void gemm_kernel(
    const unsigned short* __restrict__ Abuf, const unsigned short* __restrict__ BT,
    const float* __restrict__ scale, const float* __restrict__ shift,
    void* __restrict__ outp, int gridN) {
  __shared__ u32x4 lsA[3][1024], lsB[3][1024];  // 3 x (16KB + 16KB)
  // XCD-chunked swizzle (gridDim.x % 8 == 0)
  const int wg = (blockIdx.x & 7) * (gridDim.x >> 3) + (blockIdx.x >> 3);
  const int bn = wg % gridN, bm = wg / gridN;
  const int t = threadIdx.x;
  const int lane = t & 63, wave = t >> 6;
  const int wm = wave >> 1, wn = wave & 1;   // 4 M-slabs x 2 N-slabs
  f32x4 acc[2][4] = {};
  const size_t arow0 = (size_t)bm * 128;
  const size_t brow0 = (size_t)bn * 128;

  // 4 gloads per wave per K-tile (2 A + 2 B), each covers 64 lanes x 16B
  auto stage = [&](int slot, int kb) {
    const int kbase = kb * 64;
#pragma unroll
    for (int i = 0; i < 2; ++i) {
      const int c = wave * 64 + i * 512 + lane;    // chunk 0..1023
      const int row = c >> 3;
      const int k16 = (c & 7) ^ (row & 7);         // inverse-swizzled source
      gload16(Abuf + (arow0 + row) * 512 + kbase + k16 * 8,
              &lsA[slot][wave * 64 + i * 512]);
      gload16(BT + (brow0 + row) * 512 + kbase + k16 * 8,
              &lsB[slot][wave * 64 + i * 512]);
    }
  };

  stage(0, 0);
  stage(1, 1);
  for (int kb = 0; kb < 8; ++kb) {
    if (kb < 7) {
      asm volatile("s_waitcnt vmcnt(4)" ::: "memory");  // tile kb landed
    } else {
      asm volatile("s_waitcnt vmcnt(0)" ::: "memory");
    }
    __builtin_amdgcn_s_barrier();
    __builtin_amdgcn_sched_barrier(0);
    if (kb + 2 < 8) stage((kb + 2) % 3, kb + 2);  // overwrites slot (kb-1)%3
    const int slot = kb % 3;
#pragma unroll
    for (int kk = 0; kk < 2; ++kk) {
      bf16x8 af[2], bfv[4];
      const int c16 = kk * 4 + (lane >> 4);
#pragma unroll
      for (int mi = 0; mi < 2; ++mi) {
        int row = wm * 32 + mi * 16 + (lane & 15);
        af[mi] = __builtin_bit_cast(bf16x8, lsA[slot][row * 8 + (c16 ^ (row & 7))]);
      }
#pragma unroll
      for (int ni = 0; ni < 4; ++ni) {
        int row = wn * 64 + ni * 16 + (lane & 15);
        bfv[ni] = __builtin_bit_cast(bf16x8, lsB[slot][row * 8 + (c16 ^ (row & 7))]);
      }
#pragma unroll
      for (int mi = 0; mi < 2; ++mi)
#pragma unroll
        for (int ni = 0; ni < 4; ++ni)
          acc[mi][ni] = __builtin_amdgcn_mfma_f32_16x16x32_bf16(af[mi], bfv[ni], acc[mi][ni], 0, 0, 0);
    }
  }
  const int colb = bn * 128 + wn * 64;
  const int rowb = bm * 128 + wm * 32;
#pragma unroll
  for (int ni = 0; ni < 4; ++ni) {
    const int col = colb + ni * 16 + (lane & 15);
    const float sc = scale[col], sh = shift[col];
#pragma unroll
    for (int mi = 0; mi < 2; ++mi) {
      const int r0 = rowb + mi * 16 + ((lane >> 4) * 4);
#pragma unroll
      for (int j = 0; j < 4; ++j) {
        float v = fmaxf(__builtin_fmaf(acc[mi][ni][j], sc, sh), 0.0f);
        if (EPI == 0) {
          ((unsigned short*)outp)[(size_t)(r0 + j) * 512 + col] = f2b(v);
        } else {
          const int row = r0 + j;
          ((float*)outp)[(((size_t)(row >> 13) * 256 + col) << 13) | (size_t)(row & 8191)] = v;
        }
      }
    }
  }
}

extern "C" void kernel_launch(void* const* d_in, const int* in_sizes, int n_in,
                              void* d_out, int out_size, void* d_ws, size_t ws_size,
                              hipStream_t stream) {
  const float* xyz1 = (const float*)d_in[0];
  const float* xyz2 = (const float*)d_in[1];
  const float* points1 = (const float*)d_in[2];
  const float* points2 = (const float*)d_in[3];
  const float* w0 = (const float*)d_in[4];
  const float* b0 = (const float*)d_in[5];
  const float* g0 = (const float*)d_in[6];
  const float* be0 = (const float*)d_in[7];
  const float* m0 = (const float*)d_in[8];
  const float* v0 = (const float*)d_in[9];
  const float* w1 = (const float*)d_in[10];
  const float* b1 = (const float*)d_in[11];
  const float* g1 = (const float*)d_in[12];
  const float* be1 = (const float*)d_in[13];
  const float* m1 = (const float*)d_in[14];
  const float* v1 = (const float*)d_in[15];

  char* ws = (char*)d_ws;
  size_t off = 0;
  auto alloc = [&](size_t bytes) {
    void* p = ws + off;
    off += (bytes + 255) & ~(size_t)255;
    return p;
  };
  unsigned short* Abuf = (unsigned short*)alloc((size_t)MTOT * CIN * 2);   // 32 MB
  unsigned short* Hbuf = (unsigned short*)alloc((size_t)MTOT * 512 * 2);   // 32 MB
  unsigned short* W0T  = (unsigned short*)alloc((size_t)512 * 512 * 2);
  unsigned short* W1T  = (unsigned short*)alloc((size_t)256 * 512 * 2);
  unsigned short* P2T  = (unsigned short*)alloc((size_t)NB * SPTS * DF * 2);
  int*   oidx = (int*)alloc((size_t)MTOT * 3 * 4);
  float* ow   = (float*)alloc((size_t)MTOT * 3 * 4);
  float* sc0 = (float*)alloc(512 * 4);
  float* sh0 = (float*)alloc(512 * 4);
  float* sc1 = (float*)alloc(256 * 4);
  float* sh1 = (float*)alloc(256 * 4);
  (void)ws_size; (void)in_sizes; (void)n_in; (void)out_size;

  params_kernel<<<1, 512, 0, stream>>>(b0, g0, be0, m0, v0, b1, g1, be1, m1, v1,
                                       sc0, sh0, sc1, sh1);
  transpose_cast_kernel<<<dim3(64, 1), 256, 0, stream>>>(w0, W0T, 512, 512, 0, 0, 8);
  transpose_cast_kernel<<<dim3(32, 1), 256, 0, stream>>>(w1, W1T, 256, 512, 0, 0, 4);
  transpose_cast_kernel<<<dim3(512, NB), 256, 0, stream>>>(
      points1, Abuf, NPTS, CIN, (long)DF * NPTS, (long)NPTS * CIN, NPTS / 64);
  transpose_cast_kernel<<<dim3(128, NB), 256, 0, stream>>>(
      points2, P2T, SPTS, DF, (long)DF * SPTS, (long)SPTS * DF, SPTS / 64);
  knn_kernel<<<512, 512, 0, stream>>>(xyz1, xyz2, oidx, ow);
  interp_kernel<<<MTOT / 4, 256, 0, stream>>>(P2T, oidx, ow, Abuf);
  gemm_kernel<0><<<dim3(256 * 4), 512, 0, stream>>>(Abuf, W0T, sc0, sh0, Hbuf, 4);
  gemm_kernel<1><<<dim3(256 * 2), 512, 0, stream>>>(Hbuf, W1T, sc1, sh1, d_out, 2);
}

// Round 5
// 108.201 us; speedup vs baseline: 1.1143x; 1.1143x over previous
//
#include <hip/hip_runtime.h>
#include <cstdint>
#include <cstddef>

typedef __attribute__((ext_vector_type(4))) float f32x4;
typedef __bf16 bf16x8 __attribute__((ext_vector_type(8)));
typedef __attribute__((ext_vector_type(4))) unsigned int u32x4;
typedef __attribute__((ext_vector_type(2))) unsigned int u32x2;

#define DEVI __device__ __forceinline__

static constexpr int NB = 4;      // batches
static constexpr int NPTS = 8192; // N query points
static constexpr int SPTS = 2048; // S source points
static constexpr int DF = 256;    // feature dim of points1/points2
static constexpr int CIN = 512;   // concat width = 2*DF = K of GEMM1
static constexpr int MTOT = NB * NPTS; // 32768 rows

DEVI unsigned short f2b(float f) {
  union { float f; unsigned u; } v; v.f = f;
  unsigned r = v.u + 0x7FFFu + ((v.u >> 16) & 1u);
  return (unsigned short)(r >> 16);
}
DEVI float b2f(unsigned short h) {
  union { unsigned u; float f; } v; v.u = ((unsigned)h) << 16;
  return v.f;
}

typedef const __attribute__((address_space(1))) unsigned int* gas_t;
typedef __attribute__((address_space(3))) unsigned int* las_t;
DEVI void gload16(const void* g, void* l) {
  // async global->LDS, 16B per lane; LDS dest = uniform base + lane*16
  __builtin_amdgcn_global_load_lds((gas_t)g, (las_t)l, 16, 0, 0);
}

// ---------------- prep: BN param folding + both weight transposes (one dispatch).
// blocks 0..63: w0 [512][512] -> W0T [512][512]; 64..95: w1 [512][256] -> W1T [256][512]
// block 96: scale/shift folding.
__global__ __launch_bounds__(256) void prep_kernel(
    const float* __restrict__ w0, const float* __restrict__ w1,
    unsigned short* __restrict__ W0T, unsigned short* __restrict__ W1T,
    const float* __restrict__ b0, const float* __restrict__ g0, const float* __restrict__ be0,
    const float* __restrict__ m0, const float* __restrict__ v0,
    const float* __restrict__ b1, const float* __restrict__ g1, const float* __restrict__ be1,
    const float* __restrict__ m1, const float* __restrict__ v1,
    float* __restrict__ sc0, float* __restrict__ sh0,
    float* __restrict__ sc1, float* __restrict__ sh1) {
  __shared__ float tile[64][65];
  const int bid = blockIdx.x;
  if (bid < 96) {
    const float* in; unsigned short* out; int cols, tpr, base;
    if (bid < 64) { in = w0; out = W0T; cols = 512; tpr = 8; base = bid; }
    else          { in = w1; out = W1T; cols = 256; tpr = 4; base = bid - 64; }
    const int tr = (base / tpr) * 64, tc = (base % tpr) * 64;
    const int lx = threadIdx.x & 63, ly = threadIdx.x >> 6;
#pragma unroll
    for (int i = ly; i < 64; i += 4)
      tile[i][lx] = in[(size_t)(tr + i) * cols + tc + lx];
    __syncthreads();
#pragma unroll
    for (int i = ly; i < 64; i += 4)
      out[(size_t)(tc + i) * 512 + tr + lx] = f2b(tile[lx][i]);
  } else {
    for (int t = threadIdx.x; t < 512; t += 256) {
      float s = g0[t] / sqrtf(v0[t] + 1e-3f);
      sc0[t] = s;
      sh0[t] = (b0[t] - m0[t]) * s + be0[t];
    }
    const int t = threadIdx.x;
    if (t < 256) {
      float s = g1[t] / sqrtf(v1[t] + 1e-3f);
      sc1[t] = s;
      sh1[t] = (b1[t] - m1[t]) * s + be1[t];
    }
  }
}

// ---------------- tiled transpose + f32->bf16 cast (points1 / points2).
__global__ __launch_bounds__(256) void transpose_cast_kernel(
    const float* __restrict__ in, unsigned short* __restrict__ out,
    int cols, int ldo, long ibs, long obs, int tilesPerRow) {
  __shared__ float tile[64][65];
  in += (size_t)blockIdx.y * ibs;
  out += (size_t)blockIdx.y * obs;
  const int tr = (blockIdx.x / tilesPerRow) * 64;
  const int tc = (blockIdx.x % tilesPerRow) * 64;
  const int lx = threadIdx.x & 63, ly = threadIdx.x >> 6;
#pragma unroll
  for (int i = ly; i < 64; i += 4)
    tile[i][lx] = in[(size_t)(tr + i) * cols + tc + lx];
  __syncthreads();
#pragma unroll
  for (int i = ly; i < 64; i += 4)
    out[(size_t)(tc + i) * ldo + tr + lx] = f2b(tile[lx][i]);
}

// ---------------- 3-NN, wave-parallel over S, branchless top-3.
__global__ __launch_bounds__(512) void knn_kernel(
    const float* __restrict__ xyz1, const float* __restrict__ xyz2,
    int* __restrict__ oidx, float* __restrict__ ow) {
  __shared__ f32x4 sp[SPTS];
  __shared__ float md[7][64][3];
  __shared__ int   mi[7][64][3];
  const int batch = blockIdx.x >> 7;           // 128 blocks per batch
  const int nbase = (blockIdx.x & 127) << 6;   // *64
  const float* xb = xyz2 + (size_t)batch * 3 * SPTS;
  for (int i = threadIdx.x; i < SPTS; i += 512) {
    float a = xb[i], b = xb[SPTS + i], c = xb[2 * SPTS + i];
    f32x4 v;
    v.x = a; v.y = b; v.z = c;
    v.w = __fadd_rn(__fadd_rn(__fmul_rn(a, a), __fmul_rn(b, b)), __fmul_rn(c, c));
    sp[i] = v;
  }
  __syncthreads();
  const int lane = threadIdx.x & 63, wave = threadIdx.x >> 6;
  const int n = nbase + lane;
  const float* q = xyz1 + (size_t)batch * 3 * NPTS;
  const float x = q[n], y = q[NPTS + n], z = q[2 * NPTS + n];
  const float qa = __fadd_rn(__fadd_rn(__fmul_rn(x, x), __fmul_rn(y, y)), __fmul_rn(z, z));
  float d0 = 3.4e38f, d1 = 3.4e38f, d2 = 3.4e38f;
  int i0 = 0, i1 = 0, i2 = 0;
  const int s0 = wave << 8;
#pragma unroll 8
  for (int s = s0; s < s0 + 256; ++s) {
    f32x4 v = sp[s];
    float dot = __builtin_fmaf(v.z, z, __builtin_fmaf(v.y, y, __fmul_rn(v.x, x)));
    float sq = __builtin_fmaf(-2.0f, dot, __fadd_rn(qa, v.w));
    const bool c0 = sq < d0, c1 = sq < d1, c2 = sq < d2;
    d2 = c1 ? d1 : (c2 ? sq : d2);
    i2 = c1 ? i1 : (c2 ? s : i2);
    d1 = c0 ? d0 : (c1 ? sq : d1);
    i1 = c0 ? i0 : (c1 ? s : i1);
    d0 = c0 ? sq : d0;
    i0 = c0 ? s : i0;
  }
  if (wave != 0) {
    md[wave - 1][lane][0] = d0; mi[wave - 1][lane][0] = i0;
    md[wave - 1][lane][1] = d1; mi[wave - 1][lane][1] = i1;
    md[wave - 1][lane][2] = d2; mi[wave - 1][lane][2] = i2;
  }
  __syncthreads();
  if (wave != 0) return;
#pragma unroll
  for (int w = 0; w < 7; ++w) {
#pragma unroll
    for (int j = 0; j < 3; ++j) {
      float sq = md[w][lane][j];
      int si = mi[w][lane][j];
      const bool c0 = sq < d0, c1 = sq < d1, c2 = sq < d2;
      d2 = c1 ? d1 : (c2 ? sq : d2);
      i2 = c1 ? i1 : (c2 ? si : i2);
      d1 = c0 ? d0 : (c1 ? sq : d1);
      i1 = c0 ? i0 : (c1 ? si : i1);
      d0 = c0 ? sq : d0;
      i0 = c0 ? si : i0;
    }
  }
  float w0 = 1.0f / fmaxf(d0, 1e-10f);
  float w1 = 1.0f / fmaxf(d1, 1e-10f);
  float w2 = 1.0f / fmaxf(d2, 1e-10f);
  float sum = __fadd_rn(__fadd_rn(w0, w1), w2);
  const int p = batch * NPTS + n;
  oidx[3 * p + 0] = i0; oidx[3 * p + 1] = i1; oidx[3 * p + 2] = i2;
  ow[3 * p + 0] = w0 / sum; ow[3 * p + 1] = w1 / sum; ow[3 * p + 2] = w2 / sum;
}

// ---------------- interpolation: one wave per point; gathers 3 contiguous bf16 rows.
__global__ __launch_bounds__(256) void interp_kernel(
    const unsigned short* __restrict__ p2t, const int* __restrict__ oidx,
    const float* __restrict__ ow, unsigned short* __restrict__ A) {
  const int lane = threadIdx.x & 63;
  const int p = blockIdx.x * 4 + (threadIdx.x >> 6);
  const int b = p >> 13;
  float a0 = 0.f, a1 = 0.f, a2 = 0.f, a3 = 0.f;
#pragma unroll
  for (int k = 0; k < 3; ++k) {
    const int id = oidx[3 * p + k];
    const float w = ow[3 * p + k];
    const unsigned short* row = p2t + ((size_t)b * SPTS + id) * DF + lane * 4;
    u32x2 v = *reinterpret_cast<const u32x2*>(row);
    a0 = __builtin_fmaf(w, b2f((unsigned short)(v.x & 0xffff)), a0);
    a1 = __builtin_fmaf(w, b2f((unsigned short)(v.x >> 16)), a1);
    a2 = __builtin_fmaf(w, b2f((unsigned short)(v.y & 0xffff)), a2);
    a3 = __builtin_fmaf(w, b2f((unsigned short)(v.y >> 16)), a3);
  }
  u32x2 o;
  o.x = (unsigned)f2b(a0) | ((unsigned)f2b(a1) << 16);
  o.y = (unsigned)f2b(a2) | ((unsigned)f2b(a3) << 16);
  *reinterpret_cast<u32x2*>(A + (size_t)p * CIN + DF + lane * 4) = o;
}

// ---------------- bf16 MFMA GEMM (R3-proven 2-phase structure).
// C[M,Nout] = A[M,512] * BT[Nout,512]^T. 128x128 tile, BK=64, 4 waves (2x2),
// 16x16x32 MFMA. global_load_lds w16, pre-swizzled source + linear LDS dest +
// XOR-swizzled ds_read. Double-buffered: STAGE(next) before compute(cur),
// __syncthreads per K-step. XCD-chunked block swizzle.
// EPI 0: H = bf16(relu(c*scale+shift)), row-major [M][512], direct stores.
// EPI 1: out f32 [B][256][N] — C-tile routed through LDS (reusing the 64KB
//        staging buffers, chunk-XOR-swizzled) then coalesced f32x4 stores
//        along n (32 lanes = contiguous 512B per channel row).
template <int EPI>
__global__ __launch_bounds__(256) void gemm_kernel(
    const unsigned short* __restrict__ Abuf, const unsigned short* __restrict__ BT,
    const float* __restrict__ scale, const float* __restrict__ shift,
    void* __restrict__ outp, int gridN) {
  __shared__ u32x4 sh[4096];  // 64KB: [0..2047]=A dbuf, [2048..4095]=B dbuf
  const int wg = (blockIdx.x & 7) * (gridDim.x >> 3) + (blockIdx.x >> 3);
  const int bn = wg % gridN, bm = wg / gridN;
  const int t = threadIdx.x;
  const int lane = t & 63, wave = t >> 6;
  const int wm = wave >> 1, wn = wave & 1;
  f32x4 acc[4][4] = {};
  const size_t arow0 = (size_t)bm * 128;
  const size_t brow0 = (size_t)bn * 128;

  auto stage = [&](int buf, int kb) {
    const int kbase = kb * 64;
#pragma unroll
    for (int i = 0; i < 4; ++i) {
      const int c = wave * 256 + i * 64 + lane;     // chunk index 0..1023
      const int row = c >> 3;
      const int k16 = (c & 7) ^ (row & 7);          // inverse-swizzled source
      gload16(Abuf + (arow0 + row) * 512 + kbase + k16 * 8,
              &sh[buf * 1024 + wave * 256 + i * 64]);
      gload16(BT + (brow0 + row) * 512 + kbase + k16 * 8,
              &sh[2048 + buf * 1024 + wave * 256 + i * 64]);
    }
  };

  stage(0, 0);
  __syncthreads();
  int cur = 0;
  for (int kb = 0; kb < 8; ++kb) {
    if (kb < 7) stage(cur ^ 1, kb + 1);  // async prefetch overlaps compute
#pragma unroll
    for (int kk = 0; kk < 2; ++kk) {
      bf16x8 af[4], bfv[4];
      const int c16 = kk * 4 + (lane >> 4);
#pragma unroll
      for (int mi = 0; mi < 4; ++mi) {
        int row = wm * 64 + mi * 16 + (lane & 15);
        af[mi] = __builtin_bit_cast(bf16x8, sh[cur * 1024 + row * 8 + (c16 ^ (row & 7))]);
      }
#pragma unroll
      for (int ni = 0; ni < 4; ++ni) {
        int row = wn * 64 + ni * 16 + (lane & 15);
        bfv[ni] = __builtin_bit_cast(bf16x8, sh[2048 + cur * 1024 + row * 8 + (c16 ^ (row & 7))]);
      }
#pragma unroll
      for (int mi = 0; mi < 4; ++mi)
#pragma unroll
        for (int ni = 0; ni < 4; ++ni)
          acc[mi][ni] = __builtin_amdgcn_mfma_f32_16x16x32_bf16(af[mi], bfv[ni], acc[mi][ni], 0, 0, 0);
    }
    __syncthreads();
    cur ^= 1;
  }

  if (EPI == 0) {
    const int colb = bn * 128 + wn * 64;
    const int rowb = bm * 128 + wm * 64;
#pragma unroll
    for (int ni = 0; ni < 4; ++ni) {
      const int col = colb + ni * 16 + (lane & 15);
      const float sc = scale[col], shv = shift[col];
#pragma unroll
      for (int mi = 0; mi < 4; ++mi) {
        const int r0 = rowb + mi * 16 + ((lane >> 4) * 4);
#pragma unroll
        for (int j = 0; j < 4; ++j) {
          float v = fmaxf(__builtin_fmaf(acc[mi][ni][j], sc, shv), 0.0f);
          ((unsigned short*)outp)[(size_t)(r0 + j) * 512 + col] = f2b(v);
        }
      }
    }
  } else {
    // phase 1: dump 128x128 f32 C-tile into LDS, chunk-XOR swizzled
    // chunk(c, rj) at index c*32 + (rj ^ (c&7)), rj = r/4
    f32x4* cf = reinterpret_cast<f32x4*>(sh);
#pragma unroll
    for (int ni = 0; ni < 4; ++ni) {
      const int c = wn * 64 + ni * 16 + (lane & 15);
#pragma unroll
      for (int mi = 0; mi < 4; ++mi) {
        const int rj = (wm * 64 + mi * 16 + ((lane >> 4) * 4)) >> 2;
        cf[c * 32 + (rj ^ (c & 7))] = acc[mi][ni];
      }
    }
    __syncthreads();
    // phase 2: coalesced stores — 32 lanes sweep rj for a fixed channel c
    const int b = (bm * 128) >> 13;
    const int n0 = (bm * 128) & 8191;
    float* op = (float*)outp;
#pragma unroll
    for (int i = 0; i < 16; ++i) {
      const int ch = t + i * 256;            // 0..4095
      const int c = ch >> 5, rj = ch & 31;
      f32x4 v = cf[c * 32 + (rj ^ (c & 7))];
      const int col = bn * 128 + c;
      const float sc = scale[col], shv = shift[col];
      f32x4 o;
      o.x = fmaxf(__builtin_fmaf(v.x, sc, shv), 0.0f);
      o.y = fmaxf(__builtin_fmaf(v.y, sc, shv), 0.0f);
      o.z = fmaxf(__builtin_fmaf(v.z, sc, shv), 0.0f);
      o.w = fmaxf(__builtin_fmaf(v.w, sc, shv), 0.0f);
      *reinterpret_cast<f32x4*>(&op[(((size_t)b * 256 + col) << 13) + n0 + rj * 4]) = o;
    }
  }
}

extern "C" void kernel_launch(void* const* d_in, const int* in_sizes, int n_in,
                              void* d_out, int out_size, void* d_ws, size_t ws_size,
                              hipStream_t stream) {
  const float* xyz1 = (const float*)d_in[0];
  const float* xyz2 = (const float*)d_in[1];
  const float* points1 = (const float*)d_in[2];
  const float* points2 = (const float*)d_in[3];
  const float* w0 = (const float*)d_in[4];
  const float* b0 = (const float*)d_in[5];
  const float* g0 = (const float*)d_in[6];
  const float* be0 = (const float*)d_in[7];
  const float* m0 = (const float*)d_in[8];
  const float* v0 = (const float*)d_in[9];
  const float* w1 = (const float*)d_in[10];
  const float* b1 = (const float*)d_in[11];
  const float* g1 = (const float*)d_in[12];
  const float* be1 = (const float*)d_in[13];
  const float* m1 = (const float*)d_in[14];
  const float* v1 = (const float*)d_in[15];

  char* ws = (char*)d_ws;
  size_t off = 0;
  auto alloc = [&](size_t bytes) {
    void* p = ws + off;
    off += (bytes + 255) & ~(size_t)255;
    return p;
  };
  unsigned short* Abuf = (unsigned short*)alloc((size_t)MTOT * CIN * 2);   // 32 MB
  unsigned short* Hbuf = (unsigned short*)alloc((size_t)MTOT * 512 * 2);   // 32 MB
  unsigned short* W0T  = (unsigned short*)alloc((size_t)512 * 512 * 2);
  unsigned short* W1T  = (unsigned short*)alloc((size_t)256 * 512 * 2);
  unsigned short* P2T  = (unsigned short*)alloc((size_t)NB * SPTS * DF * 2);
  int*   oidx = (int*)alloc((size_t)MTOT * 3 * 4);
  float* ow   = (float*)alloc((size_t)MTOT * 3 * 4);
  float* sc0 = (float*)alloc(512 * 4);
  float* sh0 = (float*)alloc(512 * 4);
  float* sc1 = (float*)alloc(256 * 4);
  float* sh1 = (float*)alloc(256 * 4);
  (void)ws_size; (void)in_sizes; (void)n_in; (void)out_size;

  prep_kernel<<<97, 256, 0, stream>>>(w0, w1, W0T, W1T,
                                      b0, g0, be0, m0, v0,
                                      b1, g1, be1, m1, v1,
                                      sc0, sh0, sc1, sh1);
  transpose_cast_kernel<<<dim3(512, NB), 256, 0, stream>>>(
      points1, Abuf, NPTS, CIN, (long)DF * NPTS, (long)NPTS * CIN, NPTS / 64);
  transpose_cast_kernel<<<dim3(128, NB), 256, 0, stream>>>(
      points2, P2T, SPTS, DF, (long)DF * SPTS, (long)SPTS * DF, SPTS / 64);
  knn_kernel<<<512, 512, 0, stream>>>(xyz1, xyz2, oidx, ow);
  interp_kernel<<<MTOT / 4, 256, 0, stream>>>(P2T, oidx, ow, Abuf);
  gemm_kernel<0><<<dim3(256 * 4), 256, 0, stream>>>(Abuf, W0T, sc0, sh0, Hbuf, 4);
  gemm_kernel<1><<<dim3(256 * 2), 256, 0, stream>>>(Hbuf, W1T, sc1, sh1, d_out, 2);
}

// Round 6
// 97.469 us; speedup vs baseline: 1.2369x; 1.1101x over previous
//
#include <hip/hip_runtime.h>
#include <cstdint>
#include <cstddef>

typedef __attribute__((ext_vector_type(4))) float f32x4;
typedef __bf16 bf16x8 __attribute__((ext_vector_type(8)));
typedef __attribute__((ext_vector_type(4))) unsigned int u32x4;
typedef __attribute__((ext_vector_type(2))) unsigned int u32x2;

#define DEVI __device__ __forceinline__

static constexpr int NB = 4;      // batches
static constexpr int NPTS = 8192; // N query points
static constexpr int SPTS = 2048; // S source points
static constexpr int DF = 256;    // feature dim of points1/points2
static constexpr int CIN = 512;   // concat width = 2*DF = K of GEMM1
static constexpr int MTOT = NB * NPTS; // 32768 rows

DEVI unsigned short f2b(float f) {
  union { float f; unsigned u; } v; v.f = f;
  unsigned r = v.u + 0x7FFFu + ((v.u >> 16) & 1u);
  return (unsigned short)(r >> 16);
}
DEVI float b2f(unsigned short h) {
  union { unsigned u; float f; } v; v.u = ((unsigned)h) << 16;
  return v.f;
}

typedef const __attribute__((address_space(1))) unsigned int* gas_t;
typedef __attribute__((address_space(3))) unsigned int* las_t;
DEVI void gload16(const void* g, void* l) {
  // async global->LDS, 16B per lane; LDS dest = uniform base + lane*16
  __builtin_amdgcn_global_load_lds((gas_t)g, (las_t)l, 16, 0, 0);
}

// ---------------- pre: ALL transposes + BN param folding in ONE dispatch.
// blocks [0,2048): points1 [B][256][8192] -> Abuf[:,0:256] (ld 512)
// blocks [2048,2560): points2 [B][256][2048] -> P2T [B][2048][256]
// blocks [2560,2624): w0 [512][512] -> W0T [512][512]
// blocks [2624,2656): w1 [512][256] -> W1T [256][512]
// block 2656: scale/shift folding
__global__ __launch_bounds__(256) void pre_kernel(
    const float* __restrict__ points1, const float* __restrict__ points2,
    const float* __restrict__ w0, const float* __restrict__ w1,
    unsigned short* __restrict__ Abuf, unsigned short* __restrict__ P2T,
    unsigned short* __restrict__ W0T, unsigned short* __restrict__ W1T,
    const float* __restrict__ b0, const float* __restrict__ g0, const float* __restrict__ be0,
    const float* __restrict__ m0, const float* __restrict__ v0,
    const float* __restrict__ b1, const float* __restrict__ g1, const float* __restrict__ be1,
    const float* __restrict__ m1, const float* __restrict__ v1,
    float* __restrict__ sc0, float* __restrict__ sh0,
    float* __restrict__ sc1, float* __restrict__ sh1) {
  __shared__ float tile[64][65];
  const int bid = blockIdx.x;
  const float* in; unsigned short* out;
  int cols, tpr, ldo, tl;
  if (bid < 2048) {
    const int b = bid >> 9; tl = bid & 511;
    in = points1 + (size_t)b * DF * NPTS;
    out = Abuf + (size_t)b * NPTS * CIN;
    cols = NPTS; tpr = 128; ldo = CIN;
  } else if (bid < 2560) {
    const int i2 = bid - 2048; const int b = i2 >> 7; tl = i2 & 127;
    in = points2 + (size_t)b * DF * SPTS;
    out = P2T + (size_t)b * SPTS * DF;
    cols = SPTS; tpr = 32; ldo = DF;
  } else if (bid < 2624) {
    tl = bid - 2560; in = w0; out = W0T; cols = 512; tpr = 8; ldo = 512;
  } else if (bid < 2656) {
    tl = bid - 2624; in = w1; out = W1T; cols = 256; tpr = 4; ldo = 512;
  } else {
    for (int t = threadIdx.x; t < 512; t += 256) {
      float s = g0[t] / sqrtf(v0[t] + 1e-3f);
      sc0[t] = s;
      sh0[t] = (b0[t] - m0[t]) * s + be0[t];
    }
    const int t = threadIdx.x;
    if (t < 256) {
      float s = g1[t] / sqrtf(v1[t] + 1e-3f);
      sc1[t] = s;
      sh1[t] = (b1[t] - m1[t]) * s + be1[t];
    }
    return;
  }
  const int tr = (tl / tpr) * 64, tc = (tl % tpr) * 64;
  const int lx = threadIdx.x & 63, ly = threadIdx.x >> 6;
#pragma unroll
  for (int i = ly; i < 64; i += 4)
    tile[i][lx] = in[(size_t)(tr + i) * cols + tc + lx];
  __syncthreads();
#pragma unroll
  for (int i = ly; i < 64; i += 4)
    out[(size_t)(tc + i) * ldo + tr + lx] = f2b(tile[lx][i]);
}

// ---------------- 3-NN, wave-parallel over S, branchless top-3.
__global__ __launch_bounds__(512) void knn_kernel(
    const float* __restrict__ xyz1, const float* __restrict__ xyz2,
    int* __restrict__ oidx, float* __restrict__ ow) {
  __shared__ f32x4 sp[SPTS];
  __shared__ float md[7][64][3];
  __shared__ int   mi[7][64][3];
  const int batch = blockIdx.x >> 7;           // 128 blocks per batch
  const int nbase = (blockIdx.x & 127) << 6;   // *64
  const float* xb = xyz2 + (size_t)batch * 3 * SPTS;
  for (int i = threadIdx.x; i < SPTS; i += 512) {
    float a = xb[i], b = xb[SPTS + i], c = xb[2 * SPTS + i];
    f32x4 v;
    v.x = a; v.y = b; v.z = c;
    v.w = __fadd_rn(__fadd_rn(__fmul_rn(a, a), __fmul_rn(b, b)), __fmul_rn(c, c));
    sp[i] = v;
  }
  __syncthreads();
  const int lane = threadIdx.x & 63, wave = threadIdx.x >> 6;
  const int n = nbase + lane;
  const float* q = xyz1 + (size_t)batch * 3 * NPTS;
  const float x = q[n], y = q[NPTS + n], z = q[2 * NPTS + n];
  const float qa = __fadd_rn(__fadd_rn(__fmul_rn(x, x), __fmul_rn(y, y)), __fmul_rn(z, z));
  float d0 = 3.4e38f, d1 = 3.4e38f, d2 = 3.4e38f;
  int i0 = 0, i1 = 0, i2 = 0;
  const int s0 = wave << 8;
#pragma unroll 8
  for (int s = s0; s < s0 + 256; ++s) {
    f32x4 v = sp[s];
    float dot = __builtin_fmaf(v.z, z, __builtin_fmaf(v.y, y, __fmul_rn(v.x, x)));
    float sq = __builtin_fmaf(-2.0f, dot, __fadd_rn(qa, v.w));
    const bool c0 = sq < d0, c1 = sq < d1, c2 = sq < d2;
    d2 = c1 ? d1 : (c2 ? sq : d2);
    i2 = c1 ? i1 : (c2 ? s : i2);
    d1 = c0 ? d0 : (c1 ? sq : d1);
    i1 = c0 ? i0 : (c1 ? s : i1);
    d0 = c0 ? sq : d0;
    i0 = c0 ? s : i0;
  }
  if (wave != 0) {
    md[wave - 1][lane][0] = d0; mi[wave - 1][lane][0] = i0;
    md[wave - 1][lane][1] = d1; mi[wave - 1][lane][1] = i1;
    md[wave - 1][lane][2] = d2; mi[wave - 1][lane][2] = i2;
  }
  __syncthreads();
  if (wave != 0) return;
#pragma unroll
  for (int w = 0; w < 7; ++w) {
#pragma unroll
    for (int j = 0; j < 3; ++j) {
      float sq = md[w][lane][j];
      int si = mi[w][lane][j];
      const bool c0 = sq < d0, c1 = sq < d1, c2 = sq < d2;
      d2 = c1 ? d1 : (c2 ? sq : d2);
      i2 = c1 ? i1 : (c2 ? si : i2);
      d1 = c0 ? d0 : (c1 ? sq : d1);
      i1 = c0 ? i0 : (c1 ? si : i1);
      d0 = c0 ? sq : d0;
      i0 = c0 ? si : i0;
    }
  }
  float w0 = 1.0f / fmaxf(d0, 1e-10f);
  float w1 = 1.0f / fmaxf(d1, 1e-10f);
  float w2 = 1.0f / fmaxf(d2, 1e-10f);
  float sum = __fadd_rn(__fadd_rn(w0, w1), w2);
  const int p = batch * NPTS + n;
  oidx[3 * p + 0] = i0; oidx[3 * p + 1] = i1; oidx[3 * p + 2] = i2;
  ow[3 * p + 0] = w0 / sum; ow[3 * p + 1] = w1 / sum; ow[3 * p + 2] = w2 / sum;
}

// ---------------- interpolation: one wave per point; gathers 3 contiguous bf16 rows.
__global__ __launch_bounds__(256) void interp_kernel(
    const unsigned short* __restrict__ p2t, const int* __restrict__ oidx,
    const float* __restrict__ ow, unsigned short* __restrict__ A) {
  const int lane = threadIdx.x & 63;
  const int p = blockIdx.x * 4 + (threadIdx.x >> 6);
  const int b = p >> 13;
  float a0 = 0.f, a1 = 0.f, a2 = 0.f, a3 = 0.f;
#pragma unroll
  for (int k = 0; k < 3; ++k) {
    const int id = oidx[3 * p + k];
    const float w = ow[3 * p + k];
    const unsigned short* row = p2t + ((size_t)b * SPTS + id) * DF + lane * 4;
    u32x2 v = *reinterpret_cast<const u32x2*>(row);
    a0 = __builtin_fmaf(w, b2f((unsigned short)(v.x & 0xffff)), a0);
    a1 = __builtin_fmaf(w, b2f((unsigned short)(v.x >> 16)), a1);
    a2 = __builtin_fmaf(w, b2f((unsigned short)(v.y & 0xffff)), a2);
    a3 = __builtin_fmaf(w, b2f((unsigned short)(v.y >> 16)), a3);
  }
  u32x2 o;
  o.x = (unsigned)f2b(a0) | ((unsigned)f2b(a1) << 16);
  o.y = (unsigned)f2b(a2) | ((unsigned)f2b(a3) << 16);
  *reinterpret_cast<u32x2*>(A + (size_t)p * CIN + DF + lane * 4) = o;
}

// ---------------- GEMM1: 256x256 tile, BK=64, 8 waves (2Mx4N), acc[8][4].
// H[M,512] = bf16(relu((A[M,512]*W0T^T)*scale+shift)). 2-phase dbuf
// (proven discipline), global_load_lds w16 pre-swizzled source, 128KB LDS.
__global__ __launch_bounds__(512, 2) void gemm1_kernel(
    const unsigned short* __restrict__ Abuf, const unsigned short* __restrict__ BT,
    const float* __restrict__ scale, const float* __restrict__ shift,
    unsigned short* __restrict__ H) {
  __shared__ u32x4 lsA[2][2048];  // 64KB
  __shared__ u32x4 lsB[2][2048];  // 64KB
  const int wg = (blockIdx.x & 7) * (gridDim.x >> 3) + (blockIdx.x >> 3);
  const int bn = wg & 1, bm = wg >> 1;
  const int t = threadIdx.x;
  const int lane = t & 63, wave = t >> 6;
  const int wm = wave >> 2, wn = wave & 3;  // 2 M-slabs(128) x 4 N-slabs(64)
  f32x4 acc[8][4] = {};
  const size_t arow0 = (size_t)bm * 256;
  const size_t brow0 = (size_t)bn * 256;

  auto stage = [&](int buf, int kb) {
    const int kbase = kb * 64;
#pragma unroll
    for (int i = 0; i < 4; ++i) {
      const int c = t + 512 * i;            // chunk 0..2047
      const int row = c >> 3;
      const int k16 = (c & 7) ^ (row & 7);  // inverse-swizzled source
      gload16(Abuf + (arow0 + row) * 512 + kbase + k16 * 8,
              &lsA[buf][512 * i + wave * 64]);
      gload16(BT + (brow0 + row) * 512 + kbase + k16 * 8,
              &lsB[buf][512 * i + wave * 64]);
    }
  };

  stage(0, 0);
  __syncthreads();
  int cur = 0;
  for (int kb = 0; kb < 8; ++kb) {
    if (kb < 7) stage(cur ^ 1, kb + 1);  // async prefetch overlaps compute
#pragma unroll
    for (int kk = 0; kk < 2; ++kk) {
      bf16x8 af[8], bfv[4];
      const int c16 = kk * 4 + (lane >> 4);
#pragma unroll
      for (int mi = 0; mi < 8; ++mi) {
        int row = wm * 128 + mi * 16 + (lane & 15);
        af[mi] = __builtin_bit_cast(bf16x8, lsA[cur][row * 8 + (c16 ^ (row & 7))]);
      }
#pragma unroll
      for (int ni = 0; ni < 4; ++ni) {
        int row = wn * 64 + ni * 16 + (lane & 15);
        bfv[ni] = __builtin_bit_cast(bf16x8, lsB[cur][row * 8 + (c16 ^ (row & 7))]);
      }
#pragma unroll
      for (int mi = 0; mi < 8; ++mi)
#pragma unroll
        for (int ni = 0; ni < 4; ++ni)
          acc[mi][ni] = __builtin_amdgcn_mfma_f32_16x16x32_bf16(af[mi], bfv[ni], acc[mi][ni], 0, 0, 0);
    }
    __syncthreads();
    cur ^= 1;
  }
  const int colb = bn * 256 + wn * 64;
  const int rowb = bm * 256 + wm * 128;
#pragma unroll
  for (int ni = 0; ni < 4; ++ni) {
    const int col = colb + ni * 16 + (lane & 15);
    const float sc = scale[col], shv = shift[col];
#pragma unroll
    for (int mi = 0; mi < 8; ++mi) {
      const int r0 = rowb + mi * 16 + ((lane >> 4) * 4);
#pragma unroll
      for (int j = 0; j < 4; ++j) {
        float v = fmaxf(__builtin_fmaf(acc[mi][ni][j], sc, shv), 0.0f);
        H[(size_t)(r0 + j) * 512 + col] = f2b(v);
      }
    }
  }
}

// ---------------- GEMM2 (128x128, 4 waves, 2-phase dbuf; R4-proven).
// out f32 [B][256][N]: C-tile routed through LDS then coalesced f32x4 stores.
__global__ __launch_bounds__(256) void gemm2_kernel(
    const unsigned short* __restrict__ Abuf, const unsigned short* __restrict__ BT,
    const float* __restrict__ scale, const float* __restrict__ shift,
    float* __restrict__ outp, int gridN) {
  __shared__ u32x4 sh[4096];  // 64KB: [0..2047]=A dbuf, [2048..4095]=B dbuf
  const int wg = (blockIdx.x & 7) * (gridDim.x >> 3) + (blockIdx.x >> 3);
  const int bn = wg % gridN, bm = wg / gridN;
  const int t = threadIdx.x;
  const int lane = t & 63, wave = t >> 6;
  const int wm = wave >> 1, wn = wave & 1;
  f32x4 acc[4][4] = {};
  const size_t arow0 = (size_t)bm * 128;
  const size_t brow0 = (size_t)bn * 128;

  auto stage = [&](int buf, int kb) {
    const int kbase = kb * 64;
#pragma unroll
    for (int i = 0; i < 4; ++i) {
      const int c = wave * 256 + i * 64 + lane;     // chunk index 0..1023
      const int row = c >> 3;
      const int k16 = (c & 7) ^ (row & 7);          // inverse-swizzled source
      gload16(Abuf + (arow0 + row) * 512 + kbase + k16 * 8,
              &sh[buf * 1024 + wave * 256 + i * 64]);
      gload16(BT + (brow0 + row) * 512 + kbase + k16 * 8,
              &sh[2048 + buf * 1024 + wave * 256 + i * 64]);
    }
  };

  stage(0, 0);
  __syncthreads();
  int cur = 0;
  for (int kb = 0; kb < 8; ++kb) {
    if (kb < 7) stage(cur ^ 1, kb + 1);
#pragma unroll
    for (int kk = 0; kk < 2; ++kk) {
      bf16x8 af[4], bfv[4];
      const int c16 = kk * 4 + (lane >> 4);
#pragma unroll
      for (int mi = 0; mi < 4; ++mi) {
        int row = wm * 64 + mi * 16 + (lane & 15);
        af[mi] = __builtin_bit_cast(bf16x8, sh[cur * 1024 + row * 8 + (c16 ^ (row & 7))]);
      }
#pragma unroll
      for (int ni = 0; ni < 4; ++ni) {
        int row = wn * 64 + ni * 16 + (lane & 15);
        bfv[ni] = __builtin_bit_cast(bf16x8, sh[2048 + cur * 1024 + row * 8 + (c16 ^ (row & 7))]);
      }
#pragma unroll
      for (int mi = 0; mi < 4; ++mi)
#pragma unroll
        for (int ni = 0; ni < 4; ++ni)
          acc[mi][ni] = __builtin_amdgcn_mfma_f32_16x16x32_bf16(af[mi], bfv[ni], acc[mi][ni], 0, 0, 0);
    }
    __syncthreads();
    cur ^= 1;
  }

  // phase 1: dump 128x128 f32 C-tile into LDS, chunk-XOR swizzled
  f32x4* cf = reinterpret_cast<f32x4*>(sh);
#pragma unroll
  for (int ni = 0; ni < 4; ++ni) {
    const int c = wn * 64 + ni * 16 + (lane & 15);
#pragma unroll
    for (int mi = 0; mi < 4; ++mi) {
      const int rj = (wm * 64 + mi * 16 + ((lane >> 4) * 4)) >> 2;
      cf[c * 32 + (rj ^ (c & 7))] = acc[mi][ni];
    }
  }
  __syncthreads();
  // phase 2: coalesced stores — 32 lanes sweep rj for a fixed channel c
  const int b = (bm * 128) >> 13;
  const int n0 = (bm * 128) & 8191;
#pragma unroll
  for (int i = 0; i < 16; ++i) {
    const int ch = t + i * 256;            // 0..4095
    const int c = ch >> 5, rj = ch & 31;
    f32x4 v = cf[c * 32 + (rj ^ (c & 7))];
    const int col = bn * 128 + c;
    const float sc = scale[col], shv = shift[col];
    f32x4 o;
    o.x = fmaxf(__builtin_fmaf(v.x, sc, shv), 0.0f);
    o.y = fmaxf(__builtin_fmaf(v.y, sc, shv), 0.0f);
    o.z = fmaxf(__builtin_fmaf(v.z, sc, shv), 0.0f);
    o.w = fmaxf(__builtin_fmaf(v.w, sc, shv), 0.0f);
    *reinterpret_cast<f32x4*>(&outp[(((size_t)b * 256 + col) << 13) + n0 + rj * 4]) = o;
  }
}

extern "C" void kernel_launch(void* const* d_in, const int* in_sizes, int n_in,
                              void* d_out, int out_size, void* d_ws, size_t ws_size,
                              hipStream_t stream) {
  const float* xyz1 = (const float*)d_in[0];
  const float* xyz2 = (const float*)d_in[1];
  const float* points1 = (const float*)d_in[2];
  const float* points2 = (const float*)d_in[3];
  const float* w0 = (const float*)d_in[4];
  const float* b0 = (const float*)d_in[5];
  const float* g0 = (const float*)d_in[6];
  const float* be0 = (const float*)d_in[7];
  const float* m0 = (const float*)d_in[8];
  const float* v0 = (const float*)d_in[9];
  const float* w1 = (const float*)d_in[10];
  const float* b1 = (const float*)d_in[11];
  const float* g1 = (const float*)d_in[12];
  const float* be1 = (const float*)d_in[13];
  const float* m1 = (const float*)d_in[14];
  const float* v1 = (const float*)d_in[15];

  char* ws = (char*)d_ws;
  size_t off = 0;
  auto alloc = [&](size_t bytes) {
    void* p = ws + off;
    off += (bytes + 255) & ~(size_t)255;
    return p;
  };
  unsigned short* Abuf = (unsigned short*)alloc((size_t)MTOT * CIN * 2);   // 32 MB
  unsigned short* Hbuf = (unsigned short*)alloc((size_t)MTOT * 512 * 2);   // 32 MB
  unsigned short* W0T  = (unsigned short*)alloc((size_t)512 * 512 * 2);
  unsigned short* W1T  = (unsigned short*)alloc((size_t)256 * 512 * 2);
  unsigned short* P2T  = (unsigned short*)alloc((size_t)NB * SPTS * DF * 2);
  int*   oidx = (int*)alloc((size_t)MTOT * 3 * 4);
  float* ow   = (float*)alloc((size_t)MTOT * 3 * 4);
  float* sc0 = (float*)alloc(512 * 4);
  float* sh0 = (float*)alloc(512 * 4);
  float* sc1 = (float*)alloc(256 * 4);
  float* sh1 = (float*)alloc(256 * 4);
  (void)ws_size; (void)in_sizes; (void)n_in; (void)out_size;

  pre_kernel<<<2657, 256, 0, stream>>>(points1, points2, w0, w1,
                                       Abuf, P2T, W0T, W1T,
                                       b0, g0, be0, m0, v0,
                                       b1, g1, be1, m1, v1,
                                       sc0, sh0, sc1, sh1);
  knn_kernel<<<512, 512, 0, stream>>>(xyz1, xyz2, oidx, ow);
  interp_kernel<<<MTOT / 4, 256, 0, stream>>>(P2T, oidx, ow, Abuf);
  gemm1_kernel<<<dim3(256), 512, 0, stream>>>(Abuf, W0T, sc0, sh0, Hbuf);
  gemm2_kernel<<<dim3(256 * 2), 256, 0, stream>>>(Hbuf, W1T, sc1, sh1, (float*)d_out, 2);
}

// Round 7
// 87.168 us; speedup vs baseline: 1.3831x; 1.1182x over previous
//
#include <hip/hip_runtime.h>
#include <cstdint>
#include <cstddef>

typedef __attribute__((ext_vector_type(4))) float f32x4;
typedef __bf16 bf16x8 __attribute__((ext_vector_type(8)));
typedef __attribute__((ext_vector_type(4))) unsigned int u32x4;
typedef __attribute__((ext_vector_type(2))) unsigned int u32x2;

#define DEVI __device__ __forceinline__

static constexpr int NB = 4;      // batches
static constexpr int NPTS = 8192; // N query points
static constexpr int SPTS = 2048; // S source points
static constexpr int DF = 256;    // feature dim of points1/points2
static constexpr int CIN = 512;   // concat width = 2*DF = K of GEMM1
static constexpr int MTOT = NB * NPTS; // 32768 rows

DEVI unsigned short f2b(float f) {
  union { float f; unsigned u; } v; v.f = f;
  unsigned r = v.u + 0x7FFFu + ((v.u >> 16) & 1u);
  return (unsigned short)(r >> 16);
}
DEVI float b2f(unsigned short h) {
  union { unsigned u; float f; } v; v.u = ((unsigned)h) << 16;
  return v.f;
}

typedef const __attribute__((address_space(1))) unsigned int* gas_t;
typedef __attribute__((address_space(3))) unsigned int* las_t;
DEVI void gload16(const void* g, void* l) {
  // async global->LDS, 16B per lane; LDS dest = uniform base + lane*16
  __builtin_amdgcn_global_load_lds((gas_t)g, (las_t)l, 16, 0, 0);
}

// ---------------- fused pre + knn: ONE dispatch, independent block roles.
// blocks [0,512): 3-NN (latency-bound — scheduled first)
// blocks [512,2560): points1 [B][256][8192] -> Abuf[:,0:256] (ld 512)
// blocks [2560,3072): points2 [B][256][2048] -> P2T [B][2048][256]
// blocks [3072,3136): w0 -> W0T ; [3136,3168): w1 -> W1T ; 3168: BN fold
// LDS: 43.5KB union (knn sp/md/mi  |  transpose tile) -> 3 blocks/CU.
__global__ __launch_bounds__(512) void preknn_kernel(
    const float* __restrict__ xyz1, const float* __restrict__ xyz2,
    const float* __restrict__ points1, const float* __restrict__ points2,
    const float* __restrict__ w0, const float* __restrict__ w1,
    unsigned short* __restrict__ Abuf, unsigned short* __restrict__ P2T,
    unsigned short* __restrict__ W0T, unsigned short* __restrict__ W1T,
    int* __restrict__ oidx, float* __restrict__ ow,
    const float* __restrict__ b0, const float* __restrict__ g0, const float* __restrict__ be0,
    const float* __restrict__ m0, const float* __restrict__ v0,
    const float* __restrict__ b1, const float* __restrict__ g1, const float* __restrict__ be1,
    const float* __restrict__ m1, const float* __restrict__ v1,
    float* __restrict__ sc0, float* __restrict__ sh0,
    float* __restrict__ sc1, float* __restrict__ sh1) {
  __shared__ __align__(16) char ldsbuf[43520];
  const int bid = blockIdx.x;

  if (bid < 512) {
    // ---- 3-NN, wave-parallel over S, branchless top-3 (byte-identical math)
    f32x4* sp = reinterpret_cast<f32x4*>(ldsbuf);                       // 32768B
    float (*md)[64][3] = reinterpret_cast<float(*)[64][3]>(ldsbuf + 32768);  // 5376B
    int   (*mi)[64][3] = reinterpret_cast<int(*)[64][3]>(ldsbuf + 38144);    // 5376B
    const int batch = bid >> 7;
    const int nbase = (bid & 127) << 6;
    const float* xb = xyz2 + (size_t)batch * 3 * SPTS;
    for (int i = threadIdx.x; i < SPTS; i += 512) {
      float a = xb[i], b = xb[SPTS + i], c = xb[2 * SPTS + i];
      f32x4 v;
      v.x = a; v.y = b; v.z = c;
      v.w = __fadd_rn(__fadd_rn(__fmul_rn(a, a), __fmul_rn(b, b)), __fmul_rn(c, c));
      sp[i] = v;
    }
    __syncthreads();
    const int lane = threadIdx.x & 63, wave = threadIdx.x >> 6;
    const int n = nbase + lane;
    const float* q = xyz1 + (size_t)batch * 3 * NPTS;
    const float x = q[n], y = q[NPTS + n], z = q[2 * NPTS + n];
    const float qa = __fadd_rn(__fadd_rn(__fmul_rn(x, x), __fmul_rn(y, y)), __fmul_rn(z, z));
    float d0 = 3.4e38f, d1 = 3.4e38f, d2 = 3.4e38f;
    int i0 = 0, i1 = 0, i2 = 0;
    const int s0 = wave << 8;
#pragma unroll 8
    for (int s = s0; s < s0 + 256; ++s) {
      f32x4 v = sp[s];
      float dot = __builtin_fmaf(v.z, z, __builtin_fmaf(v.y, y, __fmul_rn(v.x, x)));
      float sq = __builtin_fmaf(-2.0f, dot, __fadd_rn(qa, v.w));
      const bool c0 = sq < d0, c1 = sq < d1, c2 = sq < d2;
      d2 = c1 ? d1 : (c2 ? sq : d2);
      i2 = c1 ? i1 : (c2 ? s : i2);
      d1 = c0 ? d0 : (c1 ? sq : d1);
      i1 = c0 ? i0 : (c1 ? s : i1);
      d0 = c0 ? sq : d0;
      i0 = c0 ? s : i0;
    }
    if (wave != 0) {
      md[wave - 1][lane][0] = d0; mi[wave - 1][lane][0] = i0;
      md[wave - 1][lane][1] = d1; mi[wave - 1][lane][1] = i1;
      md[wave - 1][lane][2] = d2; mi[wave - 1][lane][2] = i2;
    }
    __syncthreads();
    if (wave != 0) return;
#pragma unroll
    for (int w = 0; w < 7; ++w) {
#pragma unroll
      for (int j = 0; j < 3; ++j) {
        float sq = md[w][lane][j];
        int si = mi[w][lane][j];
        const bool c0 = sq < d0, c1 = sq < d1, c2 = sq < d2;
        d2 = c1 ? d1 : (c2 ? sq : d2);
        i2 = c1 ? i1 : (c2 ? si : i2);
        d1 = c0 ? d0 : (c1 ? sq : d1);
        i1 = c0 ? i0 : (c1 ? si : i1);
        d0 = c0 ? sq : d0;
        i0 = c0 ? si : i0;
      }
    }
    float w0v = 1.0f / fmaxf(d0, 1e-10f);
    float w1v = 1.0f / fmaxf(d1, 1e-10f);
    float w2v = 1.0f / fmaxf(d2, 1e-10f);
    float sum = __fadd_rn(__fadd_rn(w0v, w1v), w2v);
    const int p = batch * NPTS + n;
    oidx[3 * p + 0] = i0; oidx[3 * p + 1] = i1; oidx[3 * p + 2] = i2;
    ow[3 * p + 0] = w0v / sum; ow[3 * p + 1] = w1v / sum; ow[3 * p + 2] = w2v / sum;
    return;
  }

  if (bid == 3168) {
    // ---- BN param folding
    for (int t = threadIdx.x; t < 512; t += 512) {
      float s = g0[t] / sqrtf(v0[t] + 1e-3f);
      sc0[t] = s;
      sh0[t] = (b0[t] - m0[t]) * s + be0[t];
    }
    const int t = threadIdx.x;
    if (t < 256) {
      float s = g1[t] / sqrtf(v1[t] + 1e-3f);
      sc1[t] = s;
      sh1[t] = (b1[t] - m1[t]) * s + be1[t];
    }
    return;
  }

  // ---- tiled transpose + f32->bf16 cast (512 threads: 8 rows/iter)
  float (*tile)[65] = reinterpret_cast<float(*)[65]>(ldsbuf);
  const float* in; unsigned short* out;
  int cols, tpr, ldo, tl;
  if (bid < 2560) {
    const int i1b = bid - 512; const int b = i1b >> 9; tl = i1b & 511;
    in = points1 + (size_t)b * DF * NPTS;
    out = Abuf + (size_t)b * NPTS * CIN;
    cols = NPTS; tpr = 128; ldo = CIN;
  } else if (bid < 3072) {
    const int i2b = bid - 2560; const int b = i2b >> 7; tl = i2b & 127;
    in = points2 + (size_t)b * DF * SPTS;
    out = P2T + (size_t)b * SPTS * DF;
    cols = SPTS; tpr = 32; ldo = DF;
  } else if (bid < 3136) {
    tl = bid - 3072; in = w0; out = W0T; cols = 512; tpr = 8; ldo = 512;
  } else {
    tl = bid - 3136; in = w1; out = W1T; cols = 256; tpr = 4; ldo = 512;
  }
  const int tr = (tl / tpr) * 64, tc = (tl % tpr) * 64;
  const int lx = threadIdx.x & 63, ly = threadIdx.x >> 6;
#pragma unroll
  for (int i = ly; i < 64; i += 8)
    tile[i][lx] = in[(size_t)(tr + i) * cols + tc + lx];
  __syncthreads();
#pragma unroll
  for (int i = ly; i < 64; i += 8)
    out[(size_t)(tc + i) * ldo + tr + lx] = f2b(tile[lx][i]);
}

// ---------------- interpolation: 2 points per wave (32 lanes x 16B per row).
__global__ __launch_bounds__(256) void interp_kernel(
    const unsigned short* __restrict__ p2t, const int* __restrict__ oidx,
    const float* __restrict__ ow, unsigned short* __restrict__ A) {
  const int l = threadIdx.x & 63;
  const int lo = l & 31;
  const int p = blockIdx.x * 8 + ((threadIdx.x >> 6) << 1) + (l >> 5);
  const int b = p >> 13;
  float a[8] = {};
#pragma unroll
  for (int k = 0; k < 3; ++k) {
    const int id = oidx[3 * p + k];
    const float w = ow[3 * p + k];
    const unsigned short* row = p2t + ((size_t)b * SPTS + id) * DF + lo * 8;
    u32x4 v = *reinterpret_cast<const u32x4*>(row);
#pragma unroll
    for (int j = 0; j < 4; ++j) {
      a[2 * j + 0] = __builtin_fmaf(w, b2f((unsigned short)(v[j] & 0xffff)), a[2 * j + 0]);
      a[2 * j + 1] = __builtin_fmaf(w, b2f((unsigned short)(v[j] >> 16)), a[2 * j + 1]);
    }
  }
  u32x4 o;
#pragma unroll
  for (int j = 0; j < 4; ++j)
    o[j] = (unsigned)f2b(a[2 * j + 0]) | ((unsigned)f2b(a[2 * j + 1]) << 16);
  *reinterpret_cast<u32x4*>(A + (size_t)p * CIN + DF + lo * 8) = o;
}

// ---------------- GEMM1: 256x256 tile, BK=64, 8 waves (2Mx4N), acc[8][4].
// H[M,512] = bf16(relu((A[M,512]*W0T^T)*scale+shift)). 2-phase dbuf,
// global_load_lds w16 pre-swizzled source, 128KB LDS.
__global__ __launch_bounds__(512, 2) void gemm1_kernel(
    const unsigned short* __restrict__ Abuf, const unsigned short* __restrict__ BT,
    const float* __restrict__ scale, const float* __restrict__ shift,
    unsigned short* __restrict__ H) {
  __shared__ u32x4 lsA[2][2048];  // 64KB
  __shared__ u32x4 lsB[2][2048];  // 64KB
  const int wg = (blockIdx.x & 7) * (gridDim.x >> 3) + (blockIdx.x >> 3);
  const int bn = wg & 1, bm = wg >> 1;
  const int t = threadIdx.x;
  const int lane = t & 63, wave = t >> 6;
  const int wm = wave >> 2, wn = wave & 3;  // 2 M-slabs(128) x 4 N-slabs(64)
  f32x4 acc[8][4] = {};
  const size_t arow0 = (size_t)bm * 256;
  const size_t brow0 = (size_t)bn * 256;

  auto stage = [&](int buf, int kb) {
    const int kbase = kb * 64;
#pragma unroll
    for (int i = 0; i < 4; ++i) {
      const int c = t + 512 * i;            // chunk 0..2047
      const int row = c >> 3;
      const int k16 = (c & 7) ^ (row & 7);  // inverse-swizzled source
      gload16(Abuf + (arow0 + row) * 512 + kbase + k16 * 8,
              &lsA[buf][512 * i + wave * 64]);
      gload16(BT + (brow0 + row) * 512 + kbase + k16 * 8,
              &lsB[buf][512 * i + wave * 64]);
    }
  };

  stage(0, 0);
  __syncthreads();
  int cur = 0;
  for (int kb = 0; kb < 8; ++kb) {
    if (kb < 7) stage(cur ^ 1, kb + 1);  // async prefetch overlaps compute
#pragma unroll
    for (int kk = 0; kk < 2; ++kk) {
      bf16x8 af[8], bfv[4];
      const int c16 = kk * 4 + (lane >> 4);
#pragma unroll
      for (int mi = 0; mi < 8; ++mi) {
        int row = wm * 128 + mi * 16 + (lane & 15);
        af[mi] = __builtin_bit_cast(bf16x8, lsA[cur][row * 8 + (c16 ^ (row & 7))]);
      }
#pragma unroll
      for (int ni = 0; ni < 4; ++ni) {
        int row = wn * 64 + ni * 16 + (lane & 15);
        bfv[ni] = __builtin_bit_cast(bf16x8, lsB[cur][row * 8 + (c16 ^ (row & 7))]);
      }
#pragma unroll
      for (int mi = 0; mi < 8; ++mi)
#pragma unroll
        for (int ni = 0; ni < 4; ++ni)
          acc[mi][ni] = __builtin_amdgcn_mfma_f32_16x16x32_bf16(af[mi], bfv[ni], acc[mi][ni], 0, 0, 0);
    }
    __syncthreads();
    cur ^= 1;
  }
  const int colb = bn * 256 + wn * 64;
  const int rowb = bm * 256 + wm * 128;
#pragma unroll
  for (int ni = 0; ni < 4; ++ni) {
    const int col = colb + ni * 16 + (lane & 15);
    const float sc = scale[col], shv = shift[col];
#pragma unroll
    for (int mi = 0; mi < 8; ++mi) {
      const int r0 = rowb + mi * 16 + ((lane >> 4) * 4);
#pragma unroll
      for (int j = 0; j < 4; ++j) {
        float v = fmaxf(__builtin_fmaf(acc[mi][ni][j], sc, shv), 0.0f);
        H[(size_t)(r0 + j) * 512 + col] = f2b(v);
      }
    }
  }
}

// ---------------- GEMM2 (128x128, 4 waves, 2-phase dbuf).
// out f32 [B][256][N]: C-tile routed through LDS then coalesced f32x4 stores.
__global__ __launch_bounds__(256) void gemm2_kernel(
    const unsigned short* __restrict__ Abuf, const unsigned short* __restrict__ BT,
    const float* __restrict__ scale, const float* __restrict__ shift,
    float* __restrict__ outp, int gridN) {
  __shared__ u32x4 sh[4096];  // 64KB: [0..2047]=A dbuf, [2048..4095]=B dbuf
  const int wg = (blockIdx.x & 7) * (gridDim.x >> 3) + (blockIdx.x >> 3);
  const int bn = wg % gridN, bm = wg / gridN;
  const int t = threadIdx.x;
  const int lane = t & 63, wave = t >> 6;
  const int wm = wave >> 1, wn = wave & 1;
  f32x4 acc[4][4] = {};
  const size_t arow0 = (size_t)bm * 128;
  const size_t brow0 = (size_t)bn * 128;

  auto stage = [&](int buf, int kb) {
    const int kbase = kb * 64;
#pragma unroll
    for (int i = 0; i < 4; ++i) {
      const int c = wave * 256 + i * 64 + lane;     // chunk index 0..1023
      const int row = c >> 3;
      const int k16 = (c & 7) ^ (row & 7);          // inverse-swizzled source
      gload16(Abuf + (arow0 + row) * 512 + kbase + k16 * 8,
              &sh[buf * 1024 + wave * 256 + i * 64]);
      gload16(BT + (brow0 + row) * 512 + kbase + k16 * 8,
              &sh[2048 + buf * 1024 + wave * 256 + i * 64]);
    }
  };

  stage(0, 0);
  __syncthreads();
  int cur = 0;
  for (int kb = 0; kb < 8; ++kb) {
    if (kb < 7) stage(cur ^ 1, kb + 1);
#pragma unroll
    for (int kk = 0; kk < 2; ++kk) {
      bf16x8 af[4], bfv[4];
      const int c16 = kk * 4 + (lane >> 4);
#pragma unroll
      for (int mi = 0; mi < 4; ++mi) {
        int row = wm * 64 + mi * 16 + (lane & 15);
        af[mi] = __builtin_bit_cast(bf16x8, sh[cur * 1024 + row * 8 + (c16 ^ (row & 7))]);
      }
#pragma unroll
      for (int ni = 0; ni < 4; ++ni) {
        int row = wn * 64 + ni * 16 + (lane & 15);
        bfv[ni] = __builtin_bit_cast(bf16x8, sh[2048 + cur * 1024 + row * 8 + (c16 ^ (row & 7))]);
      }
#pragma unroll
      for (int mi = 0; mi < 4; ++mi)
#pragma unroll
        for (int ni = 0; ni < 4; ++ni)
          acc[mi][ni] = __builtin_amdgcn_mfma_f32_16x16x32_bf16(af[mi], bfv[ni], acc[mi][ni], 0, 0, 0);
    }
    __syncthreads();
    cur ^= 1;
  }

  // phase 1: dump 128x128 f32 C-tile into LDS, chunk-XOR swizzled
  f32x4* cf = reinterpret_cast<f32x4*>(sh);
#pragma unroll
  for (int ni = 0; ni < 4; ++ni) {
    const int c = wn * 64 + ni * 16 + (lane & 15);
#pragma unroll
    for (int mi = 0; mi < 4; ++mi) {
      const int rj = (wm * 64 + mi * 16 + ((lane >> 4) * 4)) >> 2;
      cf[c * 32 + (rj ^ (c & 7))] = acc[mi][ni];
    }
  }
  __syncthreads();
  // phase 2: coalesced stores — 32 lanes sweep rj for a fixed channel c
  const int b = (bm * 128) >> 13;
  const int n0 = (bm * 128) & 8191;
#pragma unroll
  for (int i = 0; i < 16; ++i) {
    const int ch = t + i * 256;            // 0..4095
    const int c = ch >> 5, rj = ch & 31;
    f32x4 v = cf[c * 32 + (rj ^ (c & 7))];
    const int col = bn * 128 + c;
    const float sc = scale[col], shv = shift[col];
    f32x4 o;
    o.x = fmaxf(__builtin_fmaf(v.x, sc, shv), 0.0f);
    o.y = fmaxf(__builtin_fmaf(v.y, sc, shv), 0.0f);
    o.z = fmaxf(__builtin_fmaf(v.z, sc, shv), 0.0f);
    o.w = fmaxf(__builtin_fmaf(v.w, sc, shv), 0.0f);
    *reinterpret_cast<f32x4*>(&outp[(((size_t)b * 256 + col) << 13) + n0 + rj * 4]) = o;
  }
}

extern "C" void kernel_launch(void* const* d_in, const int* in_sizes, int n_in,
                              void* d_out, int out_size, void* d_ws, size_t ws_size,
                              hipStream_t stream) {
  const float* xyz1 = (const float*)d_in[0];
  const float* xyz2 = (const float*)d_in[1];
  const float* points1 = (const float*)d_in[2];
  const float* points2 = (const float*)d_in[3];
  const float* w0 = (const float*)d_in[4];
  const float* b0 = (const float*)d_in[5];
  const float* g0 = (const float*)d_in[6];
  const float* be0 = (const float*)d_in[7];
  const float* m0 = (const float*)d_in[8];
  const float* v0 = (const float*)d_in[9];
  const float* w1 = (const float*)d_in[10];
  const float* b1 = (const float*)d_in[11];
  const float* g1 = (const float*)d_in[12];
  const float* be1 = (const float*)d_in[13];
  const float* m1 = (const float*)d_in[14];
  const float* v1 = (const float*)d_in[15];

  char* ws = (char*)d_ws;
  size_t off = 0;
  auto alloc = [&](size_t bytes) {
    void* p = ws + off;
    off += (bytes + 255) & ~(size_t)255;
    return p;
  };
  unsigned short* Abuf = (unsigned short*)alloc((size_t)MTOT * CIN * 2);   // 32 MB
  unsigned short* Hbuf = (unsigned short*)alloc((size_t)MTOT * 512 * 2);   // 32 MB
  unsigned short* W0T  = (unsigned short*)alloc((size_t)512 * 512 * 2);
  unsigned short* W1T  = (unsigned short*)alloc((size_t)256 * 512 * 2);
  unsigned short* P2T  = (unsigned short*)alloc((size_t)NB * SPTS * DF * 2);
  int*   oidx = (int*)alloc((size_t)MTOT * 3 * 4);
  float* ow   = (float*)alloc((size_t)MTOT * 3 * 4);
  float* sc0 = (float*)alloc(512 * 4);
  float* sh0 = (float*)alloc(512 * 4);
  float* sc1 = (float*)alloc(256 * 4);
  float* sh1 = (float*)alloc(256 * 4);
  (void)ws_size; (void)in_sizes; (void)n_in; (void)out_size;

  preknn_kernel<<<3169, 512, 0, stream>>>(xyz1, xyz2, points1, points2, w0, w1,
                                          Abuf, P2T, W0T, W1T, oidx, ow,
                                          b0, g0, be0, m0, v0,
                                          b1, g1, be1, m1, v1,
                                          sc0, sh0, sc1, sh1);
  interp_kernel<<<MTOT / 8, 256, 0, stream>>>(P2T, oidx, ow, Abuf);
  gemm1_kernel<<<dim3(256), 512, 0, stream>>>(Abuf, W0T, sc0, sh0, Hbuf);
  gemm2_kernel<<<dim3(256 * 2), 256, 0, stream>>>(Hbuf, W1T, sc1, sh1, (float*)d_out, 2);
}